// Round 1
// baseline (42.730 us; speedup 1.0000x reference)
//
#include <hip/hip_runtime.h>
#include <hip/hip_bf16.h>

#define HH 64
#define WW 128
#define HW 8192   // H*W
#define CC 256

__device__ __forceinline__ float bf_lo(unsigned u) { return __uint_as_float(u << 16); }
__device__ __forceinline__ float bf_hi(unsigned u) { return __uint_as_float(u & 0xffff0000u); }

// Transpose [C, HW] fp32 -> [HW, C] bf16, with scale folded in.
__global__ __launch_bounds__(256) void transpose_to_bf16(
    const float* __restrict__ src, __hip_bfloat16* __restrict__ dst, float scale)
{
  __shared__ float tile[32][33];
  int tx = threadIdx.x, ty = threadIdx.y;       // block (32, 8)
  int pos0 = blockIdx.x * 32, c0 = blockIdx.y * 32;
#pragma unroll
  for (int r = 0; r < 4; ++r)
    tile[ty + r * 8][tx] = src[(size_t)(c0 + ty + r * 8) * HW + pos0 + tx] * scale;
  __syncthreads();
#pragma unroll
  for (int r = 0; r < 4; ++r)
    dst[(size_t)(pos0 + ty + r * 8) * CC + c0 + tx] =
        __float2bfloat16(tile[tx][ty + r * 8]);
}

// One wave per pixel. 4 groups of 16 lanes; each group computes one neighbor
// dot per iteration (lane q covers channels [q*16, q*16+16) -> contiguous 32B).
__global__ __launch_bounds__(256) void corr_main(
    const float* __restrict__ coords,
    const unsigned* __restrict__ f1T,   // [HW][CC] bf16, viewed as uint pairs
    const unsigned* __restrict__ f2T,
    float* __restrict__ out)
{
  int tid  = threadIdx.x;
  int wave = tid >> 6;
  int lane = tid & 63;
  int g    = lane >> 4;   // group 0..3
  int q    = lane & 15;   // lane in group
  int p    = blockIdx.x * 4 + wave;   // pixel, grid = 2048 -> p < 8192

  float x = coords[p];
  float y = coords[HW + p];
  float x0f = floorf(x), y0f = floorf(y);
  float fx = x - x0f, fy = y - y0f;
  int ix0 = (int)x0f - 4;
  int iy0 = (int)y0f - 4;

  // preload f1 channels [q*16, q*16+16) as fp32 (scale 1/16 already folded)
  const uint4* f1p = (const uint4*)(f1T + (size_t)p * 128 + q * 8);
  uint4 A0 = f1p[0], A1 = f1p[1];
  float f1v[16] = { bf_lo(A0.x), bf_hi(A0.x), bf_lo(A0.y), bf_hi(A0.y),
                    bf_lo(A0.z), bf_hi(A0.z), bf_lo(A0.w), bf_hi(A0.w),
                    bf_lo(A1.x), bf_hi(A1.x), bf_lo(A1.y), bf_hi(A1.y),
                    bf_lo(A1.z), bf_hi(A1.z), bf_lo(A1.w), bf_hi(A1.w) };

  __shared__ float dots[4][100];

  for (int t = 0; t < 25; ++t) {
    int n = t * 4 + g;            // patch index, n = u*10 + v
    int u = n / 10;               // x-offset index 0..9
    int v = n - u * 10;           // y-offset index 0..9
    int gx = ix0 + u, gy = iy0 + v;
    bool valid = (gx >= 0) && (gx < WW) && (gy >= 0) && (gy < HH);
    int pos = valid ? (gy * WW + gx) : 0;
    const uint4* f2p = (const uint4*)(f2T + (size_t)pos * 128 + q * 8);
    uint4 B0 = f2p[0], B1 = f2p[1];
    float acc =      bf_lo(B0.x) * f1v[0];
    acc = fmaf(bf_hi(B0.x), f1v[1],  acc);
    acc = fmaf(bf_lo(B0.y), f1v[2],  acc);
    acc = fmaf(bf_hi(B0.y), f1v[3],  acc);
    acc = fmaf(bf_lo(B0.z), f1v[4],  acc);
    acc = fmaf(bf_hi(B0.z), f1v[5],  acc);
    acc = fmaf(bf_lo(B0.w), f1v[6],  acc);
    acc = fmaf(bf_hi(B0.w), f1v[7],  acc);
    acc = fmaf(bf_lo(B1.x), f1v[8],  acc);
    acc = fmaf(bf_hi(B1.x), f1v[9],  acc);
    acc = fmaf(bf_lo(B1.y), f1v[10], acc);
    acc = fmaf(bf_hi(B1.y), f1v[11], acc);
    acc = fmaf(bf_lo(B1.z), f1v[12], acc);
    acc = fmaf(bf_hi(B1.z), f1v[13], acc);
    acc = fmaf(bf_lo(B1.w), f1v[14], acc);
    acc = fmaf(bf_hi(B1.w), f1v[15], acc);
    // reduce across the 16-lane group
    acc += __shfl_xor(acc, 1);
    acc += __shfl_xor(acc, 2);
    acc += __shfl_xor(acc, 4);
    acc += __shfl_xor(acc, 8);
    if (q == 0) dots[wave][n] = valid ? acc : 0.0f;
  }

  __syncthreads();

  float wx1 = fx, wx0 = 1.0f - fx, wy1 = fy, wy0 = 1.0f - fy;
  for (int k = lane; k < 81; k += 64) {
    int i = k / 9;          // x-offset index (dx = i-4)
    int j = k - i * 9;      // y-offset index (dy = j-4)
    float d00 = dots[wave][i * 10 + j];
    float d10 = dots[wave][(i + 1) * 10 + j];
    float d01 = dots[wave][i * 10 + j + 1];
    float d11 = dots[wave][(i + 1) * 10 + j + 1];
    float o = wy0 * fmaf(wx1, d10, wx0 * d00) + wy1 * fmaf(wx1, d11, wx0 * d01);
    out[(size_t)k * HW + p] = o;
  }
}

// Correct-but-slow fallback if workspace is too small (reads original layout).
__global__ __launch_bounds__(64) void corr_fallback(
    const float* __restrict__ coords, const float* __restrict__ f1,
    const float* __restrict__ f2, float* __restrict__ out)
{
  int lane = threadIdx.x;
  int p = blockIdx.x;
  float x = coords[p], y = coords[HW + p];
  float x0f = floorf(x), y0f = floorf(y);
  float fx = x - x0f, fy = y - y0f;
  int ix0 = (int)x0f - 4, iy0 = (int)y0f - 4;
  float f1v[4];
#pragma unroll
  for (int k = 0; k < 4; ++k)
    f1v[k] = f1[(size_t)(lane + 64 * k) * HW + p] * 0.0625f;
  __shared__ float dots[100];
  for (int n = 0; n < 100; ++n) {
    int u = n / 10, v = n - u * 10;
    int gx = ix0 + u, gy = iy0 + v;
    bool valid = (gx >= 0) && (gx < WW) && (gy >= 0) && (gy < HH);
    int pos = valid ? (gy * WW + gx) : 0;
    float acc = 0.0f;
#pragma unroll
    for (int k = 0; k < 4; ++k)
      acc = fmaf(f1v[k], f2[(size_t)(lane + 64 * k) * HW + pos], acc);
    acc += __shfl_xor(acc, 1);
    acc += __shfl_xor(acc, 2);
    acc += __shfl_xor(acc, 4);
    acc += __shfl_xor(acc, 8);
    acc += __shfl_xor(acc, 16);
    acc += __shfl_xor(acc, 32);
    if (lane == 0) dots[n] = valid ? acc : 0.0f;
  }
  __syncthreads();
  float wx1 = fx, wx0 = 1.0f - fx, wy1 = fy, wy0 = 1.0f - fy;
  for (int k = lane; k < 81; k += 64) {
    int i = k / 9, j = k - i * 9;
    float d00 = dots[i * 10 + j];
    float d10 = dots[(i + 1) * 10 + j];
    float d01 = dots[i * 10 + j + 1];
    float d11 = dots[(i + 1) * 10 + j + 1];
    float o = wy0 * fmaf(wx1, d10, wx0 * d00) + wy1 * fmaf(wx1, d11, wx0 * d01);
    out[(size_t)k * HW + p] = o;
  }
}

extern "C" void kernel_launch(void* const* d_in, const int* in_sizes, int n_in,
                              void* d_out, int out_size, void* d_ws, size_t ws_size,
                              hipStream_t stream) {
  const float* fmap1  = (const float*)d_in[0];
  const float* fmap2  = (const float*)d_in[1];
  const float* coords = (const float*)d_in[2];
  float* out = (float*)d_out;

  size_t need = (size_t)HW * CC * sizeof(__hip_bfloat16) * 2;  // 8 MB
  if (ws_size >= need) {
    __hip_bfloat16* f1T = (__hip_bfloat16*)d_ws;
    __hip_bfloat16* f2T = f1T + (size_t)HW * CC;
    dim3 tb(32, 8), tg(HW / 32, CC / 32);
    hipLaunchKernelGGL(transpose_to_bf16, tg, tb, 0, stream, fmap1, f1T, 0.0625f);
    hipLaunchKernelGGL(transpose_to_bf16, tg, tb, 0, stream, fmap2, f2T, 1.0f);
    corr_main<<<dim3(HW / 4), dim3(256), 0, stream>>>(
        coords, (const unsigned*)f1T, (const unsigned*)f2T, out);
  } else {
    corr_fallback<<<dim3(HW), dim3(64), 0, stream>>>(coords, fmap1, fmap2, out);
  }
}